// Round 22
// baseline (38.566 us; speedup 1.0000x reference)
//
#include <hip/hip_runtime.h>
#include <hip/hip_bf16.h>
#include <hip/hip_cooperative_groups.h>

namespace cg = cooperative_groups;

#define BB 2
#define CC 64
#define HH 128
#define WW 128
#define OC 64
#define HW (HH * WW)

typedef __attribute__((ext_vector_type(8))) short bf16x8;
typedef __attribute__((ext_vector_type(4))) float f32x4;

__device__ __forceinline__ unsigned short bfbits(float f) {
    __hip_bfloat16 h = __float2bfloat16(f);
    return __builtin_bit_cast(unsigned short, h);
}
__device__ __forceinline__ float frombits(unsigned short u) {
    unsigned int v = ((unsigned int)u) << 16;
    return __builtin_bit_cast(float, v);
}
__device__ __forceinline__ int iclamp(int v, int lo, int hi) {
    return v < lo ? lo : (v > hi ? hi : v);
}

// ws layout: Wb3 | wpk | xTb (bf16 NHWC)
#define WPK_OFF3    73728
#define XTB_OFF3    110592
#define WS3_NEED    4304896

// ---------------- weight-pack helpers (element granularity) ----------------
__device__ __forceinline__ void wpack2_elem(int idx, const float* __restrict__ Wc,
                                            unsigned short* __restrict__ Wb3)
{
    if (idx < OC * 576) {
        const int j = idx & 7;
        const int r = (idx >> 3) & 15;
        const int m = (idx >> 7) & 3;
        const int a = idx >> 9;
        const int n = a >> 3;
        const int c = (a & 7) * 8 + j;
        const int oc = m * 16 + r;
        Wb3[idx] = bfbits(Wc[oc * 576 + c * 9 + n]);
    }
}
__device__ __forceinline__ void wppack_elem(int idx, const float* __restrict__ Wp,
                                            unsigned short* __restrict__ wpk)
{
    if (idx < 32 * 576) {
        const int j = idx & 7;
        const int r = (idx >> 3) & 15;
        const int m = (idx >> 7) & 1;
        const int a = idx >> 8;
        const int n = a >> 3;
        const int c = (a & 7) * 8 + j;
        const int o = m * 16 + r;
        wpk[idx] = (o < 18) ? bfbits(Wp[o * 576 + c * 9 + n]) : (unsigned short)0;
    }
}

// ---------------- 5-phase main body (R20-proven) ----------------
__device__ __forceinline__ void main_section(
    int bxl, int t, unsigned char* smem,
    const unsigned short* __restrict__ xTb,
    const unsigned short* __restrict__ wpk,
    const unsigned short* __restrict__ Wb3,
    const float* __restrict__ bp,
    float* __restrict__ out)
{
    unsigned short* bbuf = (unsigned short*)smem;             // 36864 B
    short*   smi = (short*)(smem + 36864);                    // 576 B
    ushort4* smw = (ushort4*)(smem + 37440);                  // 2304 B
    float* const odal = (float*)smem;                         // alias: 32x32 f32

    const int bxr = (bxl & 7) * 128 + (bxl >> 3);             // XCD swizzle
    const int b   = bxr >> 9;
    const int i   = (bxr >> 2) & 127;
    const int j0  = (bxr & 3) << 5;
    const int l   = t & 63;
    const int w   = t >> 6;
    const int sh  = l >> 5;
    const int c0  = (l & 31) * 2;
    const unsigned short* xb = xTb + (((size_t)b) << 14) * 64;

    // ---- phase 1: patch staging (pure bf16 copy, 2 slots/iter) ----
#pragma unroll 6
    for (int q = 0; q < 36; ++q) {
        const int slot = w * 72 + q * 2 + sh;
        const int n   = slot >> 5;
        const int pos = slot & 31;
        const int kx = n / 3, ky = n - kx * 3;
        const int ii = i + kx - 1;
        const int jj = j0 + pos + ky - 1;
        const bool ok = ((unsigned)ii < (unsigned)HH) && ((unsigned)jj < (unsigned)WW);
        unsigned int v = 0;
        if (ok) v = *(const unsigned int*)&xb[(ii * WW + jj) * 64 + c0];
        const int row = n * 8 + (c0 >> 3);
        const int pc  = pos ^ (row & 7);
        *(unsigned int*)((char*)bbuf + row * 512 + pc * 16 + (c0 & 7) * 2) = v;
    }
    __syncthreads();

    // ---- phase 2: offset-conv MFMA ----
    {
        const int mt = w >> 1;
        const int pt = w & 1;
        const int r  = l & 15;
        const int kb = l >> 4;
        const unsigned short* wb = wpk + kb * 256 + mt * 128 + r * 8;
        f32x4 acc = {0.f, 0.f, 0.f, 0.f};
#pragma unroll 6
        for (int s = 0; s < 18; ++s) {
            const int a = s * 4 + kb;
            const bf16x8 af = *(const bf16x8*)(wb + s * 1024);
            const int pc = (pt * 16 + r) ^ (a & 7);
            const bf16x8 bf = *(const bf16x8*)&bbuf[a * 256 + pc * 8];
            acc = __builtin_amdgcn_mfma_f32_16x16x32_bf16(af, bf, acc, 0, 0, 0);
        }
        __syncthreads();               // all waves done READING bbuf
#pragma unroll
        for (int reg = 0; reg < 4; ++reg)
            odal[(mt * 16 + kb * 4 + reg) * 32 + pt * 16 + r] = acc[reg];
    }
    __syncthreads();

    // ---- phase 3: metadata (288 slots) -> LDS ----
    {
        auto mkmeta = [&](int slot) {
            const int n   = slot >> 5;
            const int pos = slot & 31;
            const int kx  = n / 3, ky = n - kx * 3;
            const float offx = odal[n * 32 + pos] + bp[n];
            const float offy = odal[(9 + n) * 32 + pos] + bp[9 + n];
            const float px = offx + (float)(kx - 1) + (float)(i + 1);
            const float py = offy + (float)(ky - 1) + (float)(j0 + pos + 1);
            const float flx = floorf(px), fly = floorf(py);
            const float qltx = fminf(fmaxf(flx,       0.f), 129.f);
            const float qlty = fminf(fmaxf(fly,       0.f), 129.f);
            const float qrbx = fminf(fmaxf(flx + 1.f, 0.f), 129.f);
            const float qrby = fminf(fmaxf(fly + 1.f, 0.f), 129.f);
            const float pxc  = fminf(fmaxf(px, 0.f), 129.f);
            const float pyc  = fminf(fmaxf(py, 0.f), 129.f);
            const float gx0 = 1.f + (qltx - pxc), gx1 = 1.f - (qrbx - pxc);
            const float gy0 = 1.f + (qlty - pyc), gy1 = 1.f - (qrby - pyc);
            const int rx0 = (int)qltx - 1, rx1 = (int)qrbx - 1;
            const int ry0 = (int)qlty - 1, ry1 = (int)qrby - 1;
            const bool vx0 = (unsigned)rx0 < (unsigned)HH, vx1 = (unsigned)rx1 < (unsigned)HH;
            const bool vy0 = (unsigned)ry0 < (unsigned)WW, vy1 = (unsigned)ry1 < (unsigned)WW;
            const float w0 = (vx0 && vy0) ? gx0 * gy0 : 0.f;   // +0
            const float w1 = (vx1 && vy1) ? gx1 * gy1 : 0.f;   // +129
            const float w2 = (vx0 && vy1) ? gx0 * gy1 : 0.f;   // +1
            const float w3 = (vx1 && vy0) ? gx1 * gy0 : 0.f;   // +128
            smi[slot] = (short)(rx0 * WW + ry0);
            smw[slot] = make_ushort4(bfbits(w0), bfbits(w1), bfbits(w2), bfbits(w3));
        };
        mkmeta(t);
        if (t < 32) mkmeta(256 + t);
    }
    __syncthreads();

    // ---- phase 4: bilinear staging (bf16 corners, 2 slots/iter) ----
#pragma unroll 6
    for (int q = 0; q < 36; ++q) {
        const int slot = w * 72 + q * 2 + sh;
        const int n   = slot >> 5;
        const int pos = slot & 31;
        const int base = (int)smi[slot];
        const ushort4 wq = smw[slot];
        const float w0 = frombits(wq.x), w1 = frombits(wq.y);
        const float w2 = frombits(wq.z), w3 = frombits(wq.w);
        const int i0 = iclamp(base,       0, HW - 1);
        const int i1 = iclamp(base + 129, 0, HW - 1);
        const int i2 = iclamp(base + 1,   0, HW - 1);
        const int i3 = iclamp(base + 128, 0, HW - 1);
        const unsigned int u0 = *(const unsigned int*)&xb[i0 * 64 + c0];
        const unsigned int u1 = *(const unsigned int*)&xb[i1 * 64 + c0];
        const unsigned int u2 = *(const unsigned int*)&xb[i2 * 64 + c0];
        const unsigned int u3 = *(const unsigned int*)&xb[i3 * 64 + c0];
        float vlo = frombits((unsigned short)u0) * w0;
        vlo = fmaf(frombits((unsigned short)u1), w1, vlo);
        vlo = fmaf(frombits((unsigned short)u2), w2, vlo);
        vlo = fmaf(frombits((unsigned short)u3), w3, vlo);
        float vhi = frombits((unsigned short)(u0 >> 16)) * w0;
        vhi = fmaf(frombits((unsigned short)(u1 >> 16)), w1, vhi);
        vhi = fmaf(frombits((unsigned short)(u2 >> 16)), w2, vhi);
        vhi = fmaf(frombits((unsigned short)(u3 >> 16)), w3, vhi);
        const unsigned int vv = (unsigned int)bfbits(vlo)
                              | ((unsigned int)bfbits(vhi) << 16);
        const int row = n * 8 + (c0 >> 3);
        const int pc  = pos ^ (row & 7);
        *(unsigned int*)((char*)bbuf + row * 512 + pc * 16 + (c0 & 7) * 2) = vv;
    }
    __syncthreads();

    // ---- phase 5: main MFMA (wave = oc-tile, 18 steps, 2 pos-tiles) ----
    {
        const int r  = l & 15;
        const int kb = l >> 4;
        const unsigned short* wbase = Wb3 + kb * 512 + w * 128 + r * 8;
        f32x4 acc0 = {0.f, 0.f, 0.f, 0.f};
        f32x4 acc1 = {0.f, 0.f, 0.f, 0.f};
#pragma unroll 3
        for (int s = 0; s < 18; ++s) {
            const int a = s * 4 + kb;
            const bf16x8 af = *(const bf16x8*)(wbase + s * 2048);
            const int pc0 = (r ^ (a & 7));
            const bf16x8 bf0 = *(const bf16x8*)&bbuf[a * 256 + pc0 * 8];
            const bf16x8 bf1 = *(const bf16x8*)&bbuf[a * 256 + (16 + pc0) * 8];
            acc0 = __builtin_amdgcn_mfma_f32_16x16x32_bf16(af, bf0, acc0, 0, 0, 0);
            acc1 = __builtin_amdgcn_mfma_f32_16x16x32_bf16(af, bf1, acc1, 0, 0, 0);
        }
#pragma unroll
        for (int reg = 0; reg < 4; ++reg) {
            const int oc = w * 16 + kb * 4 + reg;
            float* o = out + ((b * OC + oc) * HH + i) * WW + j0;
            o[r]      = acc0[reg];
            o[16 + r] = acc1[reg];
        }
    }
}

// ================= cooperative fused kernel (1 dispatch, balanced prep) ======
__global__ __launch_bounds__(256, 2) void kfused(
    const float* __restrict__ x,
    const float* __restrict__ Wc,
    const float* __restrict__ Wp,
    const float* __restrict__ bp,
    unsigned short* __restrict__ xTb,
    unsigned short* __restrict__ Wb3,
    unsigned short* __restrict__ wpk,
    float* __restrict__ out)
{
    __shared__ __align__(16) unsigned char smem[39744];   // union: tile / bbuf+meta
    const int t  = threadIdx.x;
    const int bx = blockIdx.x;

    // ---- balanced prep: ALL 1024 blocks transpose 32 pixels each ----
    {
        float* tile = (float*)smem;                       // 32*65 f32 = 8320 B
        const int b    = bx >> 9;
        const int pix0 = (bx & 511) * 32;
#pragma unroll
        for (int it = 0; it < 2; ++it) {
            const int item = it * 256 + t;                // 0..511
            const int c  = item & 63;
            const int p4 = item >> 6;                     // 0..7
            const float4 v = *(const float4*)&x[(b * 64 + c) * 16384 + pix0 + p4 * 4];
            tile[(p4 * 4 + 0) * 65 + c] = v.x;
            tile[(p4 * 4 + 1) * 65 + c] = v.y;
            tile[(p4 * 4 + 2) * 65 + c] = v.z;
            tile[(p4 * 4 + 3) * 65 + c] = v.w;
        }
        __syncthreads();
#pragma unroll
        for (int it = 0; it < 2; ++it) {
            const int item = it * 256 + t;                // 0..511
            const int p  = item & 31;
            const int c4 = item >> 5;                     // 0..15
            ushort4 v;
            v.x = bfbits(tile[p * 65 + c4 * 4 + 0]);
            v.y = bfbits(tile[p * 65 + c4 * 4 + 1]);
            v.z = bfbits(tile[p * 65 + c4 * 4 + 2]);
            v.w = bfbits(tile[p * 65 + c4 * 4 + 3]);
            *(ushort4*)&xTb[(b * 16384 + pix0 + p) * 64 + c4 * 4] = v;
        }
        // tiny weight packs on low blocks (1 elem/thread)
        if (bx < 144)                 wpack2_elem(bx * 256 + t, Wc, Wb3);
        else if (bx < 216)            wppack_elem((bx - 144) * 256 + t, Wp, wpk);
    }

    __threadfence();
    cg::this_grid().sync();

    main_section(bx, t, smem, xTb, wpk, Wb3, bp, out);
}

// ================= non-cooperative fallback (R20-proven, 40.7us) =========
__global__ __launch_bounds__(256) void kprep(
    const float* __restrict__ x,
    const float* __restrict__ Wc,
    const float* __restrict__ Wp,
    unsigned short* __restrict__ xTb,
    unsigned short* __restrict__ Wb3,
    unsigned short* __restrict__ wpk)
{
    __shared__ float tile[64 * 65];
    const int t  = threadIdx.x;
    const int bx = blockIdx.x;
    if (bx < 512) {
        const int b    = bx >> 8;
        const int pix0 = (bx & 255) * 64;
#pragma unroll
        for (int it = 0; it < 4; ++it) {
            const int item = it * 256 + t;
            const int c  = item & 63;
            const int p4 = item >> 6;
            const float4 v = *(const float4*)&x[(b * 64 + c) * 16384 + pix0 + p4 * 4];
            tile[(p4 * 4 + 0) * 65 + c] = v.x;
            tile[(p4 * 4 + 1) * 65 + c] = v.y;
            tile[(p4 * 4 + 2) * 65 + c] = v.z;
            tile[(p4 * 4 + 3) * 65 + c] = v.w;
        }
        __syncthreads();
#pragma unroll
        for (int it = 0; it < 4; ++it) {
            const int item = it * 256 + t;
            const int p  = item & 63;
            const int c4 = item >> 6;
            ushort4 v;
            v.x = bfbits(tile[p * 65 + c4 * 4 + 0]);
            v.y = bfbits(tile[p * 65 + c4 * 4 + 1]);
            v.z = bfbits(tile[p * 65 + c4 * 4 + 2]);
            v.w = bfbits(tile[p * 65 + c4 * 4 + 3]);
            *(ushort4*)&xTb[(b * 16384 + pix0 + p) * 64 + c4 * 4] = v;
        }
    } else if (bx < 656) {
        wpack2_elem((bx - 512) * 256 + t, Wc, Wb3);
    } else {
        wppack_elem((bx - 656) * 256 + t, Wp, wpk);
    }
}

__global__ __launch_bounds__(256, 2) void kmain(
    const unsigned short* __restrict__ xTb,
    const unsigned short* __restrict__ wpk,
    const unsigned short* __restrict__ Wb3,
    const float* __restrict__ bp,
    float* __restrict__ out)
{
    __shared__ __align__(16) unsigned char smem[39744];
    main_section(blockIdx.x, threadIdx.x, smem, xTb, wpk, Wb3, bp, out);
}

extern "C" void kernel_launch(void* const* d_in, const int* in_sizes, int n_in,
                              void* d_out, int out_size, void* d_ws, size_t ws_size,
                              hipStream_t stream) {
    const float* x  = (const float*)d_in[0];
    const float* Wp = (const float*)d_in[1];
    const float* bp = (const float*)d_in[2];
    const float* Wc = (const float*)d_in[3];
    float* out = (float*)d_out;
    unsigned char* ws = (unsigned char*)d_ws;
    unsigned short* Wb3 = (unsigned short*)ws;
    unsigned short* wpk = (unsigned short*)(ws + WPK_OFF3);
    unsigned short* xTb = (unsigned short*)(ws + XTB_OFF3);

    // deterministic, capture-safe queries: can the whole 1024-block grid co-reside?
    int maxb = 0, ncu = 0, dev = 0;
    hipGetDevice(&dev);
    hipDeviceGetAttribute(&ncu, hipDeviceAttributeMultiprocessorCount, dev);
    hipOccupancyMaxActiveBlocksPerMultiprocessor(&maxb, (const void*)kfused, 256, 0);
    bool coop = ((long)maxb * ncu >= BB * HH * 4);

    if (coop) {
        void* args[] = {(void*)&x, (void*)&Wc, (void*)&Wp, (void*)&bp,
                        (void*)&xTb, (void*)&Wb3, (void*)&wpk, (void*)&out};
        hipError_t e = hipLaunchCooperativeKernel((const void*)kfused,
                                                  dim3(BB * HH * 4), dim3(256),
                                                  args, 0, stream);
        if (e == hipSuccess) return;
        // fall through to 2-kernel path on launch failure
    }
    kprep<<<dim3(728), dim3(256), 0, stream>>>(x, Wc, Wp, xTb, Wb3, wpk);
    kmain<<<dim3(BB * HH * 4), dim3(256), 0, stream>>>(xTb, wpk, Wb3, bp, out);
}